// Round 6
// baseline (147.509 us; speedup 1.0000x reference)
//
#include <hip/hip_runtime.h>

// ---- types ----
typedef _Float16 halfx8 __attribute__((ext_vector_type(8)));
typedef float floatx4 __attribute__((ext_vector_type(4)));
typedef float floatx2 __attribute__((ext_vector_type(2)));

#define GLOBAL_AS __attribute__((address_space(1)))
#define LDS_AS __attribute__((address_space(3)))

// async global->LDS, 16B per lane; LDS dest = wave-uniform base + lane*16
__device__ __forceinline__ void async_copy_16(const void* g, void* l) {
    __builtin_amdgcn_global_load_lds((GLOBAL_AS void*)g, (LDS_AS void*)l, 16, 0, 0);
}

// problem dims
#define PM 16384
#define PD 768
#define PA 51
#define NBLK 256u

// Math identity (verified): logits = x @ (Wa@We)^T + (Wa@b_embed + b_attr).

// Pre-fragmented B layout: frag(ks,n) = 1KB block at half-index (ks*4+n)*512;
// lane L, elem j holds Wc[n*16 + (L&15)][ks*32 + (L>>4)*8 + j].
__device__ __forceinline__ size_t fragidx(int a, int d) {
    return (size_t)(d >> 5) * 2048 + (size_t)(a >> 4) * 512
         + (size_t)((a & 15) | (((d >> 3) & 3) << 4)) * 8 + (d & 7);
}

// ================= prep: fragmented W_comb + b_comb + counter zero ===========
// Separate launch so wfrag/bc cross a kernel boundary (runtime coherence).
// 95 blocks x 4 waves = 380 waves; 377 used.
__global__ __launch_bounds__(256) void prep_kernel(
    const float* __restrict__ We, const float* __restrict__ be,
    const float* __restrict__ Wa, const float* __restrict__ ba,
    _Float16* __restrict__ wfrag, float* __restrict__ bc,
    unsigned int* __restrict__ counter)
{
    const int wave = threadIdx.x >> 6;
    const int lane = threadIdx.x & 63;
    const int Wu = __builtin_amdgcn_readfirstlane((int)blockIdx.x * 4 + wave);

    if (Wu < 312) {
        // wc[a][d] = sum_k Wa[a][k] * We[k][d]; 2 attrs x 64 cols per wave.
        const int pair = Wu / 12;
        const int dchunk = Wu - pair * 12;
        const int a0 = pair * 2;
        const bool has1 = (a0 + 1 < PA);
        const int d = dchunk * 64 + lane;
        const float* wa0 = Wa + (size_t)a0 * PD;                 // wave-uniform -> s_load
        const float* wa1 = Wa + (size_t)(has1 ? a0 + 1 : a0) * PD;
        float acc0 = 0.f, acc1 = 0.f;
        #pragma unroll 32
        for (int k = 0; k < PD; ++k) {
            float w = We[(size_t)k * PD + d];   // coalesced 256B/wave
            acc0 = fmaf(w, wa0[k], acc0);
            acc1 = fmaf(w, wa1[k], acc1);
        }
        wfrag[fragidx(a0, d)] = (_Float16)acc0;
        if (has1) wfrag[fragidx(a0 + 1, d)] = (_Float16)acc1;
    } else if (Wu < 325) {
        // zero pad rows 51..63 so B reads defined data
        const int r = PA + (Wu - 312);
        #pragma unroll
        for (int j = 0; j < 12; ++j)
            wfrag[fragidx(r, j * 64 + lane)] = (_Float16)0.f;
    } else if (Wu < 376) {
        // bc[a] = dot(Wa[a], b_embed) + b_attr[a]; one wave per attr
        const int a = Wu - 325;
        float p = 0.f;
        #pragma unroll
        for (int j = 0; j < 12; ++j) {
            int k = j * 64 + lane;
            p = fmaf(Wa[(size_t)a * PD + k], be[k], p);
        }
        #pragma unroll
        for (int off = 32; off; off >>= 1) p += __shfl_down(p, off);
        if (lane == 0) bc[a] = p + ba[a];
    } else if (Wu == 376) {
        if (lane == 0) *counter = 0u;            // reset spin barrier each replay
    }
}

// ================= fused GEMM + BN: contention-free stats ====================
// 256 blocks x 256 thr (4 waves, 1 block/CU by LDS). K-loop/staging identical
// to R5 (proven). Stats: per-block {sum,ssq} packed into ONE 8-B agent atomic
// store at a DISTINCT address (part[block][col]) -- zero same-line RMW
// serialization. After spin barrier each block reduces the 256x64 partials
// itself (coalesced, L2-hot).
__global__ void __launch_bounds__(256, 1) gemm_bn_kernel(
    const float* __restrict__ X,        // [16384][768] fp32
    const _Float16* __restrict__ Wfrag, // 96KB pre-fragmented
    const float* __restrict__ bc,       // [64]
    const float* __restrict__ gamma,
    const float* __restrict__ beta,
    float* __restrict__ out,            // [16384][51]
    unsigned long long* __restrict__ part,  // [256][64] packed {sum,ssq}
    unsigned int* __restrict__ counter)
{
    __shared__ __attribute__((aligned(16))) _Float16 Bh[24 * 4 * 512]; // 96 KB
    __shared__ __attribute__((aligned(16))) float Atile[4][3][16 * 64]; // 48 KB
    __shared__ float s_sum[64];
    __shared__ float s_ssq[64];
    __shared__ float redS[256];
    __shared__ float redQ[256];
    __shared__ float s_scale[64];
    __shared__ float s_shift[64];

    const int tid = threadIdx.x;
    const int wave = tid >> 6;          // 0..3
    const int lane = tid & 63;
    const int quad = lane >> 4;
    const int l16 = lane & 15;
    const int m0 = (int)blockIdx.x * 64 + wave * 16;   // my 16 rows

    if (tid < 64) { s_sum[tid] = 0.f; s_ssq[tid] = 0.f; }

    // ---- stage B once: 96 x 1KB chunks, 24 per wave, lane-linear ----
    #pragma unroll
    for (int j = 0; j < 24; ++j) {
        int ch = wave * 24 + j;                        // 0..95
        async_copy_16((const char*)Wfrag + (size_t)ch * 1024 + (size_t)lane * 16,
                      (char*)Bh + (size_t)ch * 1024);
    }
    asm volatile("" ::: "memory");

    // ---- A staging: 16 rows x 64 cols fp32 = 4 KB = 4 issues, XOR swizzle ----
    auto stageA = [&](int buf, int kt) {
        #pragma unroll
        for (int j = 0; j < 4; ++j) {
            int r = j * 4 + (lane >> 4);               // 0..15
            int c = lane & 15;
            int csw = (c & 8) | ((c & 7) ^ (r & 7));
            async_copy_16(X + (size_t)(m0 + r) * PD + kt + csw * 4,
                          (char*)&Atile[wave][buf][0] + (size_t)(j * 64) * 16);
        }
        asm volatile("" ::: "memory");
    };

    floatx4 acc[4];
    #pragma unroll
    for (int n = 0; n < 4; ++n) acc[n] = (floatx4){0.f, 0.f, 0.f, 0.f};

    // prologue: 3-deep A prefetch; barrier only for B visibility
    stageA(0, 0);
    stageA(1, 64);
    stageA(2, 128);
    asm volatile("s_waitcnt vmcnt(12)\n\ts_barrier" ::: "memory"); // B done, A in flight

    // ---- barrier-free K-loop: 12 macro-steps x 2 k-steps (R5-proven) ----
    #pragma unroll
    for (int mm = 0; mm < 12; ++mm) {
        if (mm <= 9)       asm volatile("s_waitcnt vmcnt(8)" ::: "memory");
        else if (mm == 10) asm volatile("s_waitcnt vmcnt(4)" ::: "memory");
        else               asm volatile("s_waitcnt vmcnt(0)" ::: "memory");
        const float* At = &Atile[wave][mm % 3][0];
        #pragma unroll
        for (int km = 0; km < 2; ++km) {
            const int ks = mm * 2 + km;
            int cc = km * 8 + quad * 2;
            int s3 = l16 & 7;
            floatx4 p0 = *(const floatx4*)&At[l16 * 64 + (((cc & 8) | ((cc & 7) ^ s3)) << 2)];
            floatx4 p1 = *(const floatx4*)&At[l16 * 64 + ((((cc + 1) & 8) | (((cc + 1) & 7) ^ s3)) << 2)];
            halfx8 af;
            af[0] = (_Float16)p0[0]; af[1] = (_Float16)p0[1];
            af[2] = (_Float16)p0[2]; af[3] = (_Float16)p0[3];
            af[4] = (_Float16)p1[0]; af[5] = (_Float16)p1[1];
            af[6] = (_Float16)p1[2]; af[7] = (_Float16)p1[3];
            #pragma unroll
            for (int n = 0; n < 4; ++n) {
                halfx8 bf = *(const halfx8*)&Bh[(size_t)(ks * 4 + n) * 512 + (size_t)lane * 8];
                acc[n] = __builtin_amdgcn_mfma_f32_16x16x32_f16(af, bf, acc[n], 0, 0, 0);
            }
        }
        if (mm + 3 < 12) stageA(mm % 3, (mm + 3) * 64);
    }

    // epilogue: D col = n*16 + (lane&15), row = m0 + quad*4 + r (verified layout)
    float keep[4][4];
    #pragma unroll
    for (int n = 0; n < 4; ++n) {
        int col = n * 16 + l16;
        if (col < PA) {
            float bv = bc[col];
            float ps = 0.f, pss = 0.f;
            #pragma unroll
            for (int r = 0; r < 4; ++r) {
                float v = acc[n][r] + bv;
                keep[n][r] = v;
                ps += v; pss += v * v;
            }
            atomicAdd(&s_sum[col], ps);       // LDS atomics (fast, local)
            atomicAdd(&s_ssq[col], pss);
        }
    }
    __syncthreads();

    // ---- publish per-block partials: 64 packed 8-B atomic stores, distinct addrs ----
    if (tid < 64) {
        union { floatx2 f; unsigned long long u; } v;
        v.f = (floatx2){s_sum[tid], s_ssq[tid]};
        __hip_atomic_store(&part[(size_t)blockIdx.x * 64 + tid], v.u,
                           __ATOMIC_RELAXED, __HIP_MEMORY_SCOPE_AGENT);
    }
    __syncthreads();   // drains vmcnt: stores globally visible before arrive

    // ---- spin barrier (R5-proven): relaxed polls, one acquire ----
    if (tid == 0) {
        __hip_atomic_fetch_add(counter, 1u, __ATOMIC_ACQ_REL, __HIP_MEMORY_SCOPE_AGENT);
        while (__hip_atomic_load(counter, __ATOMIC_RELAXED, __HIP_MEMORY_SCOPE_AGENT) < NBLK)
            __builtin_amdgcn_s_sleep(8);
        (void)__hip_atomic_load(counter, __ATOMIC_ACQUIRE, __HIP_MEMORY_SCOPE_AGENT);
    }
    __syncthreads();

    // ---- reduce partials: thread (q=tid>>6, col=tid&63) sums quarter q ----
    {
        const int col = tid & 63;
        const int q = tid >> 6;
        float rs = 0.f, rq = 0.f;
        #pragma unroll 8
        for (int i = q * 64; i < q * 64 + 64; ++i) {     // coalesced 512B/wave
            union { unsigned long long u; floatx2 f; } v;
            v.u = __hip_atomic_load(&part[(size_t)i * 64 + col],
                                    __ATOMIC_RELAXED, __HIP_MEMORY_SCOPE_AGENT);
            rs += v.f[0]; rq += v.f[1];
        }
        redS[tid] = rs; redQ[tid] = rq;
    }
    __syncthreads();

    // ---- BN coefficients once per col ----
    const float invB = 1.0f / (float)PM;
    if (tid < PA) {
        float s  = redS[tid] + redS[64 + tid] + redS[128 + tid] + redS[192 + tid];
        float ss = redQ[tid] + redQ[64 + tid] + redQ[128 + tid] + redQ[192 + tid];
        float mean = s * invB;
        float var  = ss * invB - mean * mean;
        float inv  = rsqrtf(var + 1e-5f);
        float sc = gamma[tid] * inv;
        s_scale[tid] = sc;
        s_shift[tid] = beta[tid] - mean * sc;
    }
    __syncthreads();

    // ---- BN finalize from registers ----
    #pragma unroll
    for (int n = 0; n < 4; ++n) {
        int col = n * 16 + l16;
        if (col < PA) {
            float sc = s_scale[col], sh = s_shift[col];
            int rowb = m0 + quad * 4;
            #pragma unroll
            for (int r = 0; r < 4; ++r)
                out[(size_t)(rowb + r) * PA + col] = keep[n][r] * sc + sh;
        }
    }
}

// ------------------- launch -------------------
extern "C" void kernel_launch(void* const* d_in, const int* in_sizes, int n_in,
                              void* d_out, int out_size, void* d_ws, size_t ws_size,
                              hipStream_t stream) {
    const float* x       = (const float*)d_in[0];
    const float* W_embed = (const float*)d_in[1];
    const float* b_embed = (const float*)d_in[2];
    const float* W_attr  = (const float*)d_in[3];
    const float* b_attr  = (const float*)d_in[4];
    const float* gamma   = (const float*)d_in[5];
    const float* beta    = (const float*)d_in[6];
    float* out = (float*)d_out;

    char* ws = (char*)d_ws;
    _Float16* wfrag       = (_Float16*)(ws);              // 98304 B
    float* bc             = (float*)(ws + 98304);         // 256 B
    unsigned int* counter = (unsigned int*)(ws + 98560);  // 4 B
    unsigned long long* part = (unsigned long long*)(ws + 98816); // 256*64*8 = 131072 B

    prep_kernel<<<95, 256, 0, stream>>>(W_embed, b_embed, W_attr, b_attr,
                                        wfrag, bc, counter);
    gemm_bn_kernel<<<256, 256, 0, stream>>>(x, wfrag, bc, gamma, beta, out,
                                            part, counter);
}

// Round 7
// 141.615 us; speedup vs baseline: 1.0416x; 1.0416x over previous
//
#include <hip/hip_runtime.h>

// ---- types ----
typedef _Float16 halfx8 __attribute__((ext_vector_type(8)));
typedef float floatx4 __attribute__((ext_vector_type(4)));
typedef float floatx2 __attribute__((ext_vector_type(2)));

#define GLOBAL_AS __attribute__((address_space(1)))
#define LDS_AS __attribute__((address_space(3)))

// async global->LDS, 16B per lane; LDS dest = wave-uniform base + lane*16
__device__ __forceinline__ void async_copy_16(const void* g, void* l) {
    __builtin_amdgcn_global_load_lds((GLOBAL_AS void*)g, (LDS_AS void*)l, 16, 0, 0);
}

// problem dims
#define PM 16384
#define PD 768
#define PA 51
#define NBLK 256u

// Math identity (verified): logits = x @ (Wa@We)^T + (Wa@b_embed + b_attr).

// Pre-fragmented B layout: frag(ks,n) = 1KB block at half-index (ks*4+n)*512;
// lane L, elem j holds Wc[n*16 + (L&15)][ks*32 + (L>>4)*8 + j].
__device__ __forceinline__ size_t fragidx(int a, int d) {
    return (size_t)(d >> 5) * 2048 + (size_t)(a >> 4) * 512
         + (size_t)((a & 15) | (((d >> 3) & 3) << 4)) * 8 + (d & 7);
}

// ================= prep: fragmented W_comb + b_comb + counter zero ===========
// Separate launch so wfrag/bc cross a kernel boundary (runtime coherence).
__global__ __launch_bounds__(256) void prep_kernel(
    const float* __restrict__ We, const float* __restrict__ be,
    const float* __restrict__ Wa, const float* __restrict__ ba,
    _Float16* __restrict__ wfrag, float* __restrict__ bc,
    unsigned int* __restrict__ counter)
{
    const int wave = threadIdx.x >> 6;
    const int lane = threadIdx.x & 63;
    const int Wu = __builtin_amdgcn_readfirstlane((int)blockIdx.x * 4 + wave);

    if (Wu < 312) {
        // wc[a][d] = sum_k Wa[a][k] * We[k][d]; 2 attrs x 64 cols per wave.
        const int pair = Wu / 12;
        const int dchunk = Wu - pair * 12;
        const int a0 = pair * 2;
        const bool has1 = (a0 + 1 < PA);
        const int d = dchunk * 64 + lane;
        const float* wa0 = Wa + (size_t)a0 * PD;                 // wave-uniform -> s_load
        const float* wa1 = Wa + (size_t)(has1 ? a0 + 1 : a0) * PD;
        float acc0 = 0.f, acc1 = 0.f;
        #pragma unroll 32
        for (int k = 0; k < PD; ++k) {
            float w = We[(size_t)k * PD + d];   // coalesced 256B/wave
            acc0 = fmaf(w, wa0[k], acc0);
            acc1 = fmaf(w, wa1[k], acc1);
        }
        wfrag[fragidx(a0, d)] = (_Float16)acc0;
        if (has1) wfrag[fragidx(a0 + 1, d)] = (_Float16)acc1;
    } else if (Wu < 325) {
        // zero pad rows 51..63 so B reads defined data
        const int r = PA + (Wu - 312);
        #pragma unroll
        for (int j = 0; j < 12; ++j)
            wfrag[fragidx(r, j * 64 + lane)] = (_Float16)0.f;
    } else if (Wu < 376) {
        // bc[a] = dot(Wa[a], b_embed) + b_attr[a]; one wave per attr
        const int a = Wu - 325;
        float p = 0.f;
        #pragma unroll
        for (int j = 0; j < 12; ++j) {
            int k = j * 64 + lane;
            p = fmaf(Wa[(size_t)a * PD + k], be[k], p);
        }
        #pragma unroll
        for (int off = 32; off; off >>= 1) p += __shfl_down(p, off);
        if (lane == 0) bc[a] = p + ba[a];
    } else if (Wu == 376) {
        if (lane == 0) *counter = 0u;            // reset last-block counter each replay
    }
}

// ================= GEMM: barrier-free K-loop, NO global barrier ==============
// 256 blocks x 256 thr (4 waves, 1 block/CU by LDS). K-loop/staging identical
// to R5/R6 (proven). Epilogue: write logits (bias-added) + per-block packed
// partials; LAST block (fetch_add) reduces partials -> scale/shift. No block
// ever waits on another (kernel boundary provides the ordering for bn_kernel).
__global__ void __launch_bounds__(256, 1) gemm_kernel(
    const float* __restrict__ X,        // [16384][768] fp32
    const _Float16* __restrict__ Wfrag, // 96KB pre-fragmented
    const float* __restrict__ bc,       // [64]
    const float* __restrict__ gamma,
    const float* __restrict__ beta,
    float* __restrict__ logits,         // [16384][51] ws
    unsigned long long* __restrict__ part,  // [256][64] packed {sum,ssq}
    unsigned int* __restrict__ counter,
    float* __restrict__ ss)             // [0..63]=scale, [64..127]=shift
{
    __shared__ __attribute__((aligned(16))) _Float16 Bh[24 * 4 * 512]; // 96 KB
    __shared__ __attribute__((aligned(16))) float Atile[4][3][16 * 64]; // 48 KB
    __shared__ float s_sum[64];
    __shared__ float s_ssq[64];
    __shared__ float redS[256];
    __shared__ float redQ[256];
    __shared__ int s_last;

    const int tid = threadIdx.x;
    const int wave = tid >> 6;          // 0..3
    const int lane = tid & 63;
    const int quad = lane >> 4;
    const int l16 = lane & 15;
    const int m0 = (int)blockIdx.x * 64 + wave * 16;   // my 16 rows

    if (tid < 64) { s_sum[tid] = 0.f; s_ssq[tid] = 0.f; }

    // ---- stage B once: 96 x 1KB chunks, 24 per wave, lane-linear ----
    #pragma unroll
    for (int j = 0; j < 24; ++j) {
        int ch = wave * 24 + j;                        // 0..95
        async_copy_16((const char*)Wfrag + (size_t)ch * 1024 + (size_t)lane * 16,
                      (char*)Bh + (size_t)ch * 1024);
    }
    asm volatile("" ::: "memory");

    // ---- A staging: 16 rows x 64 cols fp32 = 4 KB = 4 issues, XOR swizzle ----
    auto stageA = [&](int buf, int kt) {
        #pragma unroll
        for (int j = 0; j < 4; ++j) {
            int r = j * 4 + (lane >> 4);               // 0..15
            int c = lane & 15;
            int csw = (c & 8) | ((c & 7) ^ (r & 7));
            async_copy_16(X + (size_t)(m0 + r) * PD + kt + csw * 4,
                          (char*)&Atile[wave][buf][0] + (size_t)(j * 64) * 16);
        }
        asm volatile("" ::: "memory");
    };

    floatx4 acc[4];
    #pragma unroll
    for (int n = 0; n < 4; ++n) acc[n] = (floatx4){0.f, 0.f, 0.f, 0.f};

    // prologue: 3-deep A prefetch; barrier only for B visibility
    stageA(0, 0);
    stageA(1, 64);
    stageA(2, 128);
    asm volatile("s_waitcnt vmcnt(12)\n\ts_barrier" ::: "memory"); // B done, A in flight

    // ---- barrier-free K-loop: 12 macro-steps x 2 k-steps (R5/R6-proven) ----
    #pragma unroll
    for (int mm = 0; mm < 12; ++mm) {
        if (mm <= 9)       asm volatile("s_waitcnt vmcnt(8)" ::: "memory");
        else if (mm == 10) asm volatile("s_waitcnt vmcnt(4)" ::: "memory");
        else               asm volatile("s_waitcnt vmcnt(0)" ::: "memory");
        const float* At = &Atile[wave][mm % 3][0];
        #pragma unroll
        for (int km = 0; km < 2; ++km) {
            const int ks = mm * 2 + km;
            int cc = km * 8 + quad * 2;
            int s3 = l16 & 7;
            floatx4 p0 = *(const floatx4*)&At[l16 * 64 + (((cc & 8) | ((cc & 7) ^ s3)) << 2)];
            floatx4 p1 = *(const floatx4*)&At[l16 * 64 + ((((cc + 1) & 8) | (((cc + 1) & 7) ^ s3)) << 2)];
            halfx8 af;
            af[0] = (_Float16)p0[0]; af[1] = (_Float16)p0[1];
            af[2] = (_Float16)p0[2]; af[3] = (_Float16)p0[3];
            af[4] = (_Float16)p1[0]; af[5] = (_Float16)p1[1];
            af[6] = (_Float16)p1[2]; af[7] = (_Float16)p1[3];
            #pragma unroll
            for (int n = 0; n < 4; ++n) {
                halfx8 bf = *(const halfx8*)&Bh[(size_t)(ks * 4 + n) * 512 + (size_t)lane * 8];
                acc[n] = __builtin_amdgcn_mfma_f32_16x16x32_f16(af, bf, acc[n], 0, 0, 0);
            }
        }
        if (mm + 3 < 12) stageA(mm % 3, (mm + 3) * 64);
    }

    // epilogue: D col = n*16 + (lane&15), row = m0 + quad*4 + r (verified layout)
    #pragma unroll
    for (int n = 0; n < 4; ++n) {
        int col = n * 16 + l16;
        if (col < PA) {
            float bv = bc[col];
            float ps = 0.f, pss = 0.f;
            int rowb = m0 + quad * 4;
            #pragma unroll
            for (int r = 0; r < 4; ++r) {
                float v = acc[n][r] + bv;
                logits[(size_t)(rowb + r) * PA + col] = v;   // bias-added logits
                ps += v; pss += v * v;
            }
            atomicAdd(&s_sum[col], ps);       // LDS atomics (fast, local)
            atomicAdd(&s_ssq[col], pss);
        }
    }
    __syncthreads();

    // ---- publish per-block partials: 64 packed 8-B atomic stores, distinct addrs ----
    if (tid < 64) {
        union { floatx2 f; unsigned long long u; } v;
        v.f = (floatx2){s_sum[tid], s_ssq[tid]};
        __hip_atomic_store(&part[(size_t)blockIdx.x * 64 + tid], v.u,
                           __ATOMIC_RELAXED, __HIP_MEMORY_SCOPE_AGENT);
    }
    __syncthreads();   // drains vmem: partial stores + logits done before arrive

    // ---- last-block pattern: only the final arriver reduces; nobody waits ----
    if (tid == 0) {
        unsigned int old = __hip_atomic_fetch_add(counter, 1u, __ATOMIC_ACQ_REL,
                                                  __HIP_MEMORY_SCOPE_AGENT);
        s_last = (old == NBLK - 1u);
    }
    __syncthreads();
    if (s_last) {
        // reduce 256x64 partials: thread (q=tid>>6, col=tid&63) sums quarter q
        const int col = tid & 63;
        const int q = tid >> 6;
        float rs = 0.f, rq = 0.f;
        #pragma unroll 8
        for (int i = q * 64; i < q * 64 + 64; ++i) {     // coalesced 512B/wave
            union { unsigned long long u; floatx2 f; } v;
            v.u = __hip_atomic_load(&part[(size_t)i * 64 + col],
                                    __ATOMIC_RELAXED, __HIP_MEMORY_SCOPE_AGENT);
            rs += v.f[0]; rq += v.f[1];
        }
        redS[tid] = rs; redQ[tid] = rq;
        __syncthreads();
        const float invB = 1.0f / (float)PM;
        if (tid < PA) {
            float s  = redS[tid] + redS[64 + tid] + redS[128 + tid] + redS[192 + tid];
            float sq = redQ[tid] + redQ[64 + tid] + redQ[128 + tid] + redQ[192 + tid];
            float mean = s * invB;
            float var  = sq * invB - mean * mean;
            float inv  = rsqrtf(var + 1e-5f);
            float sc = gamma[tid] * inv;
            ss[tid] = sc;
            ss[64 + tid] = beta[tid] - mean * sc;   // kernel boundary publishes
        }
    }
}

// ================= BN finalize: logits * scale + shift -> out ================
// 816 blocks x 256 thr, one float4 per thread (208896 float4s exactly).
__global__ __launch_bounds__(256) void bn_kernel(
    const float* __restrict__ logits,
    const float* __restrict__ ss,       // [0..63]=scale, [64..127]=shift
    float* __restrict__ out)
{
    __shared__ float sc[64];
    __shared__ float sh[64];
    const int t = threadIdx.x;
    if (t < 64) { sc[t] = ss[t]; sh[t] = ss[64 + t]; }
    __syncthreads();

    const int idx = (int)blockIdx.x * 256 + t;      // float4 index
    floatx4 v = ((const floatx4*)logits)[idx];
    int c0 = (idx * 4) % 51;                        // compiler magic-mul
    int c1 = c0 + 1; if (c1 >= 51) c1 -= 51;
    int c2 = c1 + 1; if (c2 >= 51) c2 -= 51;
    int c3 = c2 + 1; if (c3 >= 51) c3 -= 51;
    floatx4 r;
    r[0] = v[0] * sc[c0] + sh[c0];
    r[1] = v[1] * sc[c1] + sh[c1];
    r[2] = v[2] * sc[c2] + sh[c2];
    r[3] = v[3] * sc[c3] + sh[c3];
    ((floatx4*)out)[idx] = r;
}

// ------------------- launch -------------------
extern "C" void kernel_launch(void* const* d_in, const int* in_sizes, int n_in,
                              void* d_out, int out_size, void* d_ws, size_t ws_size,
                              hipStream_t stream) {
    const float* x       = (const float*)d_in[0];
    const float* W_embed = (const float*)d_in[1];
    const float* b_embed = (const float*)d_in[2];
    const float* W_attr  = (const float*)d_in[3];
    const float* b_attr  = (const float*)d_in[4];
    const float* gamma   = (const float*)d_in[5];
    const float* beta    = (const float*)d_in[6];
    float* out = (float*)d_out;

    char* ws = (char*)d_ws;
    _Float16* wfrag       = (_Float16*)(ws);              // 98304 B
    float* bc             = (float*)(ws + 98304);         // 256 B
    unsigned int* counter = (unsigned int*)(ws + 98560);  // 4 B
    unsigned long long* part = (unsigned long long*)(ws + 98816); // 131072 B
    float* ssbuf          = (float*)(ws + 229888);        // 512 B
    float* logits         = (float*)(ws + 230400);        // 3342336 B

    prep_kernel<<<95, 256, 0, stream>>>(W_embed, b_embed, W_attr, b_attr,
                                        wfrag, bc, counter);
    gemm_kernel<<<256, 256, 0, stream>>>(x, wfrag, bc, gamma, beta,
                                         logits, part, counter, ssbuf);
    bn_kernel<<<816, 256, 0, stream>>>(logits, ssbuf, out);
}